// Round 8
// baseline (476.930 us; speedup 1.0000x reference)
//
#include <hip/hip_runtime.h>
#include <cstddef>
#include <cstdint>

typedef unsigned short ushort_t;
typedef unsigned long long ull_t;
typedef __attribute__((ext_vector_type(8))) short short8;
typedef __attribute__((ext_vector_type(4))) float f32x4;

constexpr int D_ = 512, K_ = 8192, N_ = 16384;
constexpr float MARGIN = 0.75f;   // >= 2*eps of bf16-MFMA score error (max-tail ~0.45)

// RNE float->bf16 (data has no NaN)
__device__ __forceinline__ ushort_t f2bf(float f) {
  unsigned u = __float_as_uint(f);
  return (ushort_t)((u + 0x7FFFu + ((u >> 16) & 1u)) >> 16);
}
// order-preserving float->uint flip (max-compatible)
__device__ __forceinline__ unsigned flipf(float s) {
  unsigned u = __float_as_uint(s);
  return (u & 0x80000000u) ? ~u : (u | 0x80000000u);
}
__device__ __forceinline__ float unflipf(unsigned m) {
  unsigned u = (m & 0x80000000u) ? (m ^ 0x80000000u) : ~m;
  return __uint_as_float(u);
}
__device__ __forceinline__ ull_t umax64(ull_t a, ull_t b) { return a > b ? a : b; }
__device__ __forceinline__ ull_t umin64(ull_t a, ull_t b) { return a < b ? a : b; }

__device__ __forceinline__ void gld16(void* l, const void* g) {
  __builtin_amdgcn_global_load_lds((const __attribute__((address_space(1))) void*)g,
                                   (__attribute__((address_space(3))) void*)l, 16, 0, 0);
}

// -------- zero worklist counters + rowbest (runs AFTER dist_mfma; aliases xbt) --------
__global__ __launch_bounds__(256) void init_ws(int* counters, ull_t* rowbest) {
  int t = blockIdx.x * 256 + threadIdx.x;   // grid 64*256 == N_
  rowbest[t] = 0ull;
  if (t < 2) counters[t] = 0;
}

// -------- convert x -> bf16 permuted, coalesced reads --------
// dst: xbt[tile][g(16)][kq(4)][r(128)] 16B chunks. grid 1024 = 128 tiles x 8 rowgroups.
// thread: g = tid&15, rr = tid>>4 -> 16 threads read one full 2KB row contiguously.
__global__ __launch_bounds__(256) void conv_x(const float* __restrict__ x, char* __restrict__ xbt) {
  const int tile = blockIdx.x >> 3, rg = blockIdx.x & 7;
  const int g = threadIdx.x & 15, rr = threadIdx.x >> 4;
  const int r = rg * 16 + rr;
  const float4* src = (const float4*)(x + ((size_t)(tile * 128 + r)) * D_ + g * 32);
  float4 f[8];
#pragma unroll
  for (int q = 0; q < 8; ++q) f[q] = src[q];
  char* dbase = xbt + (size_t)tile * 131072 + g * 8192 + r * 16;
#pragma unroll
  for (int kq = 0; kq < 4; ++kq) {
    float4 a = f[kq * 2], b = f[kq * 2 + 1];
    short8 v;
    v[0] = (short)f2bf(a.x); v[1] = (short)f2bf(a.y); v[2] = (short)f2bf(a.z); v[3] = (short)f2bf(a.w);
    v[4] = (short)f2bf(b.x); v[5] = (short)f2bf(b.y); v[6] = (short)f2bf(b.z); v[7] = (short)f2bf(b.w);
    *(short8*)(dbase + kq * 2048) = v;
  }
}

// -------- convert embed -> bf16 permuted + ehs = 0.5*||e||^2 fused --------
// grid 512 = 64 tiles x 8 rowgroups
__global__ __launch_bounds__(256) void conv_e(const float* __restrict__ e, char* __restrict__ ebt,
                                              float* __restrict__ ehs) {
  const int tile = blockIdx.x >> 3, rg = blockIdx.x & 7;
  const int g = threadIdx.x & 15, rr = threadIdx.x >> 4;
  const int r = rg * 16 + rr;
  const int col = tile * 128 + r;
  const float4* src = (const float4*)(e + (size_t)col * D_ + g * 32);
  float4 f[8];
  float ss = 0.f;
#pragma unroll
  for (int q = 0; q < 8; ++q) {
    f[q] = src[q];
    ss += f[q].x * f[q].x + f[q].y * f[q].y + f[q].z * f[q].z + f[q].w * f[q].w;
  }
  char* dbase = ebt + (size_t)tile * 131072 + g * 8192 + r * 16;
#pragma unroll
  for (int kq = 0; kq < 4; ++kq) {
    float4 a = f[kq * 2], b = f[kq * 2 + 1];
    short8 v;
    v[0] = (short)f2bf(a.x); v[1] = (short)f2bf(a.y); v[2] = (short)f2bf(a.z); v[3] = (short)f2bf(a.w);
    v[4] = (short)f2bf(b.x); v[5] = (short)f2bf(b.y); v[6] = (short)f2bf(b.z); v[7] = (short)f2bf(b.w);
    *(short8*)(dbase + kq * 2048) = v;
  }
  // reduce squares across the 16 g-lanes of this row
#pragma unroll
  for (int m = 1; m < 16; m <<= 1) ss += __shfl_xor(ss, m);
  if (g == 0) ehs[col] = 0.5f * ss;
}

// -------- MFMA scoring: per (row, 128-col block) packed top-1 (score|invcol) + s2 --------
// grid (128,64); XCD-swizzled; BK=64 (2 g-slabs per barrier pair)
__global__ __launch_bounds__(256, 3) void dist_mfma(const char* __restrict__ xbt,
                                                    const char* __restrict__ ebt,
                                                    const float* __restrict__ ehs,
                                                    ull_t* __restrict__ ppu,
                                                    float* __restrict__ pps2) {
  __shared__ alignas(16) char lds[32768];
  char* As = lds;            // 2 slabs of [kq(4)][r(128)] 16B chunks
  char* Bs = lds + 16384;
  const int tid = threadIdx.x, w = tid >> 6, l = tid & 63;
  // XCD-aware bijective remap: XCD k owns col-tiles [8k,8k+8), sweeps them innermost
  const int fid = blockIdx.x + blockIdx.y * 128;
  const int k8 = fid & 7, j = fid >> 3;
  const int by = k8 * 8 + (j & 7), bx = j >> 3;
  const int row0 = bx * 128, col0 = by * 128;
  const int wr = w >> 1, wc = w & 1;
  const size_t xtile = (size_t)bx * 131072;
  const size_t etile = (size_t)by * 131072;

  f32x4 acc[4][4] = {};
  for (int gp = 0; gp < 8; ++gp) {
#pragma unroll
    for (int s = 0; s < 2; ++s)
#pragma unroll
      for (int i = 0; i < 2; ++i) {
        gld16(As + s * 8192 + w * 2048 + i * 1024,
              xbt + xtile + (gp * 2 + s) * 8192 + w * 2048 + i * 1024 + l * 16);
        gld16(Bs + s * 8192 + w * 2048 + i * 1024,
              ebt + etile + (gp * 2 + s) * 8192 + w * 2048 + i * 1024 + l * 16);
      }
    __syncthreads();
#pragma unroll
    for (int s = 0; s < 2; ++s) {
      short8 a[4], b[4];
#pragma unroll
      for (int i = 0; i < 4; ++i)
        a[i] = *(const short8*)(As + s * 8192 + (l >> 4) * 2048 + (wr * 64 + i * 16 + (l & 15)) * 16);
#pragma unroll
      for (int jj = 0; jj < 4; ++jj)
        b[jj] = *(const short8*)(Bs + s * 8192 + (l >> 4) * 2048 + (wc * 64 + jj * 16 + (l & 15)) * 16);
#pragma unroll
      for (int i = 0; i < 4; ++i)
#pragma unroll
        for (int jj = 0; jj < 4; ++jj)
          acc[i][jj] = __builtin_amdgcn_mfma_f32_16x16x32_bf16(a[i], b[jj], acc[i][jj], 0, 0, 0);
    }
    __syncthreads();
  }

  // ---- epilogue: per-row packed top-1 (u64 max) + second-best score ----
  float eh[4];
  unsigned ic[4];
#pragma unroll
  for (int jj = 0; jj < 4; ++jj) {
    int col = col0 + wc * 64 + jj * 16 + (l & 15);
    eh[jj] = ehs[col];
    ic[jj] = 0xFFFFFFFFu - (unsigned)col;   // larger packed == smaller col on score tie
  }

  const int c = l & 15, g16 = l >> 4;
  ull_t fp = 0; float fs2 = -3e38f;
#pragma unroll
  for (int i = 0; i < 4; ++i) {
    ull_t pv[4]; float s2v[4];
#pragma unroll
    for (int r = 0; r < 4; ++r) {
      float v0 = acc[i][0][r] - eh[0], v1 = acc[i][1][r] - eh[1];
      float v2 = acc[i][2][r] - eh[2], v3 = acc[i][3][r] - eh[3];
      ull_t p0 = ((ull_t)flipf(v0) << 32) | ic[0];
      ull_t p1 = ((ull_t)flipf(v1) << 32) | ic[1];
      ull_t p2 = ((ull_t)flipf(v2) << 32) | ic[2];
      ull_t p3 = ((ull_t)flipf(v3) << 32) | ic[3];
      pv[r] = umax64(umax64(p0, p1), umax64(p2, p3));
      float m01 = fmaxf(v0, v1), n01 = fminf(v0, v1);
      float m23 = fmaxf(v2, v3), n23 = fminf(v2, v3);
      s2v[r] = fmaxf(fminf(m01, m23), fmaxf(n01, n23));   // 2nd of 4
    }
#pragma unroll
    for (int m = 1; m < 16; m <<= 1) {
#pragma unroll
      for (int r = 0; r < 4; ++r) {
        ull_t op = __shfl_xor(pv[r], m);
        float os2 = __shfl_xor(s2v[r], m);
        ull_t lo = umin64(pv[r], op);
        s2v[r] = fmaxf(fmaxf(s2v[r], os2), unflipf((unsigned)(lo >> 32)));
        pv[r] = umax64(pv[r], op);
      }
    }
    if ((c >> 2) == i) {
      int rsel = c & 3;
      fp  = (rsel == 0) ? pv[0]  : (rsel == 1) ? pv[1]  : (rsel == 2) ? pv[2]  : pv[3];
      fs2 = (rsel == 0) ? s2v[0] : (rsel == 1) ? s2v[1] : (rsel == 2) ? s2v[2] : s2v[3];
    }
  }
  const int rib = wr * 64 + (c >> 2) * 16 + g16 * 4 + (c & 3);   // owned row in [0,128)

  // cross-wave (wc) merge via LDS (staging area dead after final __syncthreads)
  ull_t* lp = (ull_t*)lds;              // [2][128]
  float* ls2 = (float*)(lds + 2048);    // [2][128]
  lp[wc * 128 + rib] = fp; ls2[wc * 128 + rib] = fs2;
  __syncthreads();
  if (wc == 0) {
    ull_t op = lp[128 + rib];
    float os2 = ls2[128 + rib];
    ull_t lo = umin64(fp, op);
    fs2 = fmaxf(fmaxf(fs2, os2), unflipf((unsigned)(lo >> 32)));
    fp = umax64(fp, op);
    ppu[(size_t)(row0 + rib) * 64 + by] = fp;
    pps2[(size_t)(row0 + rib) * 64 + by] = fs2;
  }
}

// -------- combine: candidates = block top-1 cols within MARGIN; s2-hit blocks -> full scan --------
__global__ __launch_bounds__(256) void combine(const ull_t* __restrict__ ppu,
                                               const float* __restrict__ pps2,
                                               int* __restrict__ wl, int* __restrict__ wl2,
                                               int* __restrict__ counters) {
  int row = (blockIdx.x * 256 + threadIdx.x) >> 6;
  int l = threadIdx.x & 63;
  ull_t p = ppu[(size_t)row * 64 + l];
  float s2 = pps2[(size_t)row * 64 + l];
  ull_t gp = p;
#pragma unroll
  for (int m = 1; m < 64; m <<= 1) gp = umax64(gp, __shfl_xor(gp, m));
  float gs = unflipf((unsigned)(gp >> 32));
  float t = gs - MARGIN;
  float s1 = unflipf((unsigned)(p >> 32));
  bool cand = (s1 >= t);
  bool ovf = (s2 >= t);
  ull_t b1 = __ballot(cand);
  ull_t b2 = __ballot(ovf);
  int n1 = __popcll(b1), n2 = __popcll(b2);
  int base1 = 0, base2 = 0;
  if (l == 0) {
    base1 = atomicAdd(&counters[0], n1);
    if (n2) base2 = atomicAdd(&counters[1], n2);
  }
  base1 = __shfl(base1, 0); base2 = __shfl(base2, 0);
  ull_t below = (1ull << l) - 1ull;
  if (cand) {
    int col = (int)(0xFFFFFFFFu - (unsigned)(p & 0xFFFFFFFFu));
    wl[base1 + __popcll(b1 & below)] = (row << 13) | col;
  }
  if (ovf) wl2[base2 + __popcll(b2 & below)] = (row << 6) | l;
}

// -------- exact fp32 scoring of single candidate cols: one wave per entry --------
__global__ __launch_bounds__(256) void cand_exact(const float* __restrict__ x,
                                                  const float* __restrict__ embed,
                                                  const float* __restrict__ ehs,
                                                  const int* __restrict__ wl,
                                                  const int* __restrict__ counters,
                                                  ull_t* __restrict__ rowbest) {
  int wid = (blockIdx.x * 256 + threadIdx.x) >> 6;
  int l = threadIdx.x & 63;
  int count = counters[0];
  for (int eidx = wid; eidx < count; eidx += 16384) {
    int entry = wl[eidx];
    int row = entry >> 13, col = entry & 8191;
    float4 xa = *(const float4*)(x + (size_t)row * D_ + l * 8);
    float4 xc = *(const float4*)(x + (size_t)row * D_ + l * 8 + 4);
    float4 ea = *(const float4*)(embed + (size_t)col * D_ + l * 8);
    float4 ec = *(const float4*)(embed + (size_t)col * D_ + l * 8 + 4);
    float s = xa.x * ea.x + xa.y * ea.y + xa.z * ea.z + xa.w * ea.w
            + xc.x * ec.x + xc.y * ec.y + xc.z * ec.z + xc.w * ec.w;
#pragma unroll
    for (int m = 1; m < 64; m <<= 1) s += __shfl_xor(s, m);
    s -= ehs[col];
    if (l == 0) {
      ull_t packed = ((ull_t)flipf(s) << 32) | (0xFFFFFFFFu - (unsigned)col);
      atomicMax(&rowbest[row], packed);
    }
  }
}

// -------- full exact fp32 scan of s2-flagged (row, block): one wave per entry (rare) --------
__global__ __launch_bounds__(256) void fb_full(const float* __restrict__ x,
                                               const float* __restrict__ embed,
                                               const float* __restrict__ ehs,
                                               const int* __restrict__ wl2,
                                               const int* __restrict__ counters,
                                               ull_t* __restrict__ rowbest) {
  int wid = (blockIdx.x * 256 + threadIdx.x) >> 6;
  int l = threadIdx.x & 63;
  int count = counters[1];
  for (int eidx = wid; eidx < count; eidx += 16384) {
    int entry = wl2[eidx];
    int row = entry >> 6;
    int c0 = (entry & 63) * 128;
    const float* xr = x + (size_t)row * D_;
    const float* e0p = embed + (size_t)(c0 + l) * D_;
    const float* e1p = embed + (size_t)(c0 + 64 + l) * D_;
    float a0 = 0.f, a1 = 0.f;
    for (int d = 0; d < D_; d += 4) {
      float4 xv = *(const float4*)(xr + d);
      float4 v0 = *(const float4*)(e0p + d);
      float4 v1 = *(const float4*)(e1p + d);
      a0 = fmaf(v0.x, xv.x, fmaf(v0.y, xv.y, fmaf(v0.z, xv.z, fmaf(v0.w, xv.w, a0))));
      a1 = fmaf(v1.x, xv.x, fmaf(v1.y, xv.y, fmaf(v1.z, xv.z, fmaf(v1.w, xv.w, a1))));
    }
    float s0 = a0 - ehs[c0 + l];
    float s1 = a1 - ehs[c0 + 64 + l];
    ull_t p0 = ((ull_t)flipf(s0) << 32) | (0xFFFFFFFFu - (unsigned)(c0 + l));
    ull_t p1 = ((ull_t)flipf(s1) << 32) | (0xFFFFFFFFu - (unsigned)(c0 + 64 + l));
    ull_t packed = umax64(p0, p1);
#pragma unroll
    for (int m = 1; m < 64; m <<= 1) packed = umax64(packed, __shfl_xor(packed, m));
    if (l == 0) atomicMax(&rowbest[row], packed);
  }
}

// -------- write all outputs: gather embed[argmax] + index-as-float --------
__global__ __launch_bounds__(256) void gather(const float* __restrict__ embed,
                                              const ull_t* __restrict__ rowbest,
                                              float* __restrict__ out) {
  int row = (blockIdx.x * 256 + threadIdx.x) >> 6;
  int l = threadIdx.x & 63;
  ull_t p = rowbest[row];
  int idx = (int)(0xFFFFFFFFu - (unsigned)(p & 0xFFFFFFFFu));
  const float4* src = (const float4*)(embed + (size_t)idx * D_);
  float4* dst = (float4*)(out + (size_t)row * D_);
  dst[l] = src[l];
  dst[l + 64] = src[l + 64];
  if (l == 0) out[(size_t)N_ * D_ + row] = (float)idx;
}

extern "C" void kernel_launch(void* const* d_in, const int* in_sizes, int n_in,
                              void* d_out, int out_size, void* d_ws, size_t ws_size,
                              hipStream_t stream) {
  const float* x = (const float*)d_in[0];     // [16384, 512]
  const float* e = (const float*)d_in[1];     // [8192, 512]
  float* out = (float*)d_out;

  char* ws = (char*)d_ws;
  // region A (0..16MB): xbt during conv/dist; worklists alias it afterwards
  char* xbt = ws;                                       // 16 MB
  int* wl = (int*)ws;                                   // 4 MB (candidate entries)
  int* wl2 = (int*)(ws + 4194304);                      // 4 MB (overflow entries)
  int* counters = (int*)(ws + 8388608);                 // 8 B
  ull_t* rowbest = (ull_t*)(ws + 8388672);              // 128 KB
  char* ebt = ws + 16777216;                            // 8 MB
  float* ehs = (float*)(ws + 25165824);                 // 32 KB
  ull_t* ppu = (ull_t*)(ws + 25198592);                 // 8 MB (N_*64 ull)
  float* pps2 = (float*)(ws + 33587200);                // 4 MB (N_*64 float)

  conv_x<<<1024, 256, 0, stream>>>(x, xbt);
  conv_e<<<512, 256, 0, stream>>>(e, ebt, ehs);
  dist_mfma<<<dim3(128, 64), 256, 0, stream>>>(xbt, ebt, ehs, ppu, pps2);
  init_ws<<<64, 256, 0, stream>>>(counters, rowbest);   // after dist_mfma: aliases xbt
  combine<<<4096, 256, 0, stream>>>(ppu, pps2, wl, wl2, counters);
  cand_exact<<<4096, 256, 0, stream>>>(x, e, ehs, wl, counters, rowbest);
  fb_full<<<4096, 256, 0, stream>>>(x, e, ehs, wl2, counters, rowbest);
  gather<<<4096, 256, 0, stream>>>(e, rowbest, out);
}

// Round 9
// 472.871 us; speedup vs baseline: 1.0086x; 1.0086x over previous
//
#include <hip/hip_runtime.h>
#include <cstddef>
#include <cstdint>

typedef unsigned short ushort_t;
typedef unsigned long long ull_t;
typedef __attribute__((ext_vector_type(8))) short short8;
typedef __attribute__((ext_vector_type(4))) float f32x4;

constexpr int D_ = 512, K_ = 8192, N_ = 16384;
constexpr float MARGIN = 0.75f;   // >= 2*eps of bf16-MFMA score error (max-tail ~0.45)

// RNE float->bf16 (data has no NaN)
__device__ __forceinline__ ushort_t f2bf(float f) {
  unsigned u = __float_as_uint(f);
  return (ushort_t)((u + 0x7FFFu + ((u >> 16) & 1u)) >> 16);
}
// order-preserving float->uint flip (max-compatible)
__device__ __forceinline__ unsigned flipf(float s) {
  unsigned u = __float_as_uint(s);
  return (u & 0x80000000u) ? ~u : (u | 0x80000000u);
}
__device__ __forceinline__ float unflipf(unsigned m) {
  unsigned u = (m & 0x80000000u) ? (m ^ 0x80000000u) : ~m;
  return __uint_as_float(u);
}
__device__ __forceinline__ ull_t umax64(ull_t a, ull_t b) { return a > b ? a : b; }
__device__ __forceinline__ ull_t umin64(ull_t a, ull_t b) { return a < b ? a : b; }

__device__ __forceinline__ void gld16(void* l, const void* g) {
  __builtin_amdgcn_global_load_lds((const __attribute__((address_space(1))) void*)g,
                                   (__attribute__((address_space(3))) void*)l, 16, 0, 0);
}

// -------- zero worklist counters + rowbest (runs AFTER dist_mfma; aliases xbt) --------
__global__ __launch_bounds__(256) void init_ws(int* counters, ull_t* rowbest) {
  int t = blockIdx.x * 256 + threadIdx.x;   // grid 64*256 == N_
  rowbest[t] = 0ull;
  if (t < 2) counters[t] = 0;
}

// -------- convert x -> bf16 permuted, coalesced reads / sector-efficient writes --------
// dst: xbt[tile][g(16)][kq(4)][r(128)] 16B chunks. grid 1024 = 128 tiles x 8 rowgroups.
__global__ __launch_bounds__(256) void conv_x(const float* __restrict__ x, char* __restrict__ xbt) {
  const int tile = blockIdx.x >> 3, rg = blockIdx.x & 7;
  const int g = threadIdx.x & 15, rr = threadIdx.x >> 4;
  const int r = rg * 16 + rr;
  const float4* src = (const float4*)(x + ((size_t)(tile * 128 + r)) * D_ + g * 32);
  float4 f[8];
#pragma unroll
  for (int q = 0; q < 8; ++q) f[q] = src[q];
  char* dbase = xbt + (size_t)tile * 131072 + g * 8192 + r * 16;
#pragma unroll
  for (int kq = 0; kq < 4; ++kq) {
    float4 a = f[kq * 2], b = f[kq * 2 + 1];
    short8 v;
    v[0] = (short)f2bf(a.x); v[1] = (short)f2bf(a.y); v[2] = (short)f2bf(a.z); v[3] = (short)f2bf(a.w);
    v[4] = (short)f2bf(b.x); v[5] = (short)f2bf(b.y); v[6] = (short)f2bf(b.z); v[7] = (short)f2bf(b.w);
    *(short8*)(dbase + kq * 2048) = v;
  }
}

// -------- convert embed -> bf16 permuted + ehs = 0.5*||e||^2 fused --------
__global__ __launch_bounds__(256) void conv_e(const float* __restrict__ e, char* __restrict__ ebt,
                                              float* __restrict__ ehs) {
  const int tile = blockIdx.x >> 3, rg = blockIdx.x & 7;
  const int g = threadIdx.x & 15, rr = threadIdx.x >> 4;
  const int r = rg * 16 + rr;
  const int col = tile * 128 + r;
  const float4* src = (const float4*)(e + (size_t)col * D_ + g * 32);
  float4 f[8];
  float ss = 0.f;
#pragma unroll
  for (int q = 0; q < 8; ++q) {
    f[q] = src[q];
    ss += f[q].x * f[q].x + f[q].y * f[q].y + f[q].z * f[q].z + f[q].w * f[q].w;
  }
  char* dbase = ebt + (size_t)tile * 131072 + g * 8192 + r * 16;
#pragma unroll
  for (int kq = 0; kq < 4; ++kq) {
    float4 a = f[kq * 2], b = f[kq * 2 + 1];
    short8 v;
    v[0] = (short)f2bf(a.x); v[1] = (short)f2bf(a.y); v[2] = (short)f2bf(a.z); v[3] = (short)f2bf(a.w);
    v[4] = (short)f2bf(b.x); v[5] = (short)f2bf(b.y); v[6] = (short)f2bf(b.z); v[7] = (short)f2bf(b.w);
    *(short8*)(dbase + kq * 2048) = v;
  }
#pragma unroll
  for (int m = 1; m < 16; m <<= 1) ss += __shfl_xor(ss, m);
  if (g == 0) ehs[col] = 0.5f * ss;
}

// -------- MFMA scoring: per (row, 128-col block) packed top-1 (score|invcol) + s2 --------
// grid (128,64); XCD-swizzled; BK=32; double-buffered LDS, ONE barrier per K-step
__global__ __launch_bounds__(256, 3) void dist_mfma(const char* __restrict__ xbt,
                                                    const char* __restrict__ ebt,
                                                    const float* __restrict__ ehs,
                                                    ull_t* __restrict__ ppu,
                                                    float* __restrict__ pps2) {
  __shared__ alignas(16) char lds[32768];   // [buf(2)][A(8K)|B(8K)]
  const int tid = threadIdx.x, w = tid >> 6, l = tid & 63;
  // XCD-aware bijective remap: XCD k owns col-tiles [8k,8k+8), sweeps them innermost
  const int fid = blockIdx.x + blockIdx.y * 128;
  const int k8 = fid & 7, j = fid >> 3;
  const int by = k8 * 8 + (j & 7), bx = j >> 3;
  const int row0 = bx * 128, col0 = by * 128;
  const int wr = w >> 1, wc = w & 1;
  const char* xsrc = xbt + (size_t)bx * 131072;
  const char* esrc = ebt + (size_t)by * 131072;

  // prologue: stage g=0 into buf0
#pragma unroll
  for (int i = 0; i < 2; ++i) {
    gld16(lds + w * 2048 + i * 1024, xsrc + w * 2048 + i * 1024 + l * 16);
    gld16(lds + 8192 + w * 2048 + i * 1024, esrc + w * 2048 + i * 1024 + l * 16);
  }
  __syncthreads();

  f32x4 acc[4][4] = {};
  for (int g = 0; g < 16; ++g) {
    char* cbase = lds + (g & 1) * 16384;
    // prefetch next slab into the other buffer (flies during ds_read+MFMA)
    if (g < 15) {
      char* nbase = lds + ((g + 1) & 1) * 16384;
#pragma unroll
      for (int i = 0; i < 2; ++i) {
        gld16(nbase + w * 2048 + i * 1024, xsrc + (g + 1) * 8192 + w * 2048 + i * 1024 + l * 16);
        gld16(nbase + 8192 + w * 2048 + i * 1024, esrc + (g + 1) * 8192 + w * 2048 + i * 1024 + l * 16);
      }
    }
    short8 a[4], b[4];
#pragma unroll
    for (int i = 0; i < 4; ++i)
      a[i] = *(const short8*)(cbase + (l >> 4) * 2048 + (wr * 64 + i * 16 + (l & 15)) * 16);
#pragma unroll
    for (int jj = 0; jj < 4; ++jj)
      b[jj] = *(const short8*)(cbase + 8192 + (l >> 4) * 2048 + (wc * 64 + jj * 16 + (l & 15)) * 16);
#pragma unroll
    for (int i = 0; i < 4; ++i)
#pragma unroll
      for (int jj = 0; jj < 4; ++jj)
        acc[i][jj] = __builtin_amdgcn_mfma_f32_16x16x32_bf16(a[i], b[jj], acc[i][jj], 0, 0, 0);
    __syncthreads();   // drains vm+lgkm: next buffer ready, current buffer free to overwrite
  }

  // ---- epilogue (f32/u32 three-phase; no u64 until the final pack) ----
  float eh[4];
  unsigned ic[4];
#pragma unroll
  for (int jj = 0; jj < 4; ++jj) {
    int col = col0 + wc * 64 + jj * 16 + (l & 15);
    eh[jj] = ehs[col];
    ic[jj] = 0xFFFFFFFFu - (unsigned)col;   // larger == smaller col on score tie; never 0
  }
  // scores in place
#pragma unroll
  for (int i = 0; i < 4; ++i)
#pragma unroll
    for (int jj = 0; jj < 4; ++jj)
#pragma unroll
      for (int r = 0; r < 4; ++r)
        acc[i][jj][r] -= eh[jj];

  // Phase A: row max (all-reduce over the 16 col-lanes)
  float mx[4][4];
#pragma unroll
  for (int i = 0; i < 4; ++i)
#pragma unroll
    for (int r = 0; r < 4; ++r)
      mx[i][r] = fmaxf(fmaxf(acc[i][0][r], acc[i][1][r]), fmaxf(acc[i][2][r], acc[i][3][r]));
#pragma unroll
  for (int m = 1; m < 16; m <<= 1)
#pragma unroll
    for (int i = 0; i < 4; ++i)
#pragma unroll
      for (int r = 0; r < 4; ++r)
        mx[i][r] = fmaxf(mx[i][r], __shfl_xor(mx[i][r], m));

  // Phase B: index (max inverted-col among elements equal to max)
  unsigned ii[4][4];
#pragma unroll
  for (int i = 0; i < 4; ++i)
#pragma unroll
    for (int r = 0; r < 4; ++r) {
      unsigned t0 = (acc[i][0][r] == mx[i][r]) ? ic[0] : 0u;
      unsigned t1 = (acc[i][1][r] == mx[i][r]) ? ic[1] : 0u;
      unsigned t2 = (acc[i][2][r] == mx[i][r]) ? ic[2] : 0u;
      unsigned t3 = (acc[i][3][r] == mx[i][r]) ? ic[3] : 0u;
      unsigned u01 = t0 > t1 ? t0 : t1, u23 = t2 > t3 ? t2 : t3;
      ii[i][r] = u01 > u23 ? u01 : u23;
    }
#pragma unroll
  for (int m = 1; m < 16; m <<= 1)
#pragma unroll
    for (int i = 0; i < 4; ++i)
#pragma unroll
      for (int r = 0; r < 4; ++r) {
        unsigned o = __shfl_xor(ii[i][r], m);
        ii[i][r] = ii[i][r] > o ? ii[i][r] : o;
      }

  // Phase C: s2 = max excluding exactly the chosen instance (ties -> s2 == max -> overflow)
  float s2[4][4];
#pragma unroll
  for (int i = 0; i < 4; ++i)
#pragma unroll
    for (int r = 0; r < 4; ++r) {
      float t0 = (ic[0] == ii[i][r]) ? -3e38f : acc[i][0][r];
      float t1 = (ic[1] == ii[i][r]) ? -3e38f : acc[i][1][r];
      float t2 = (ic[2] == ii[i][r]) ? -3e38f : acc[i][2][r];
      float t3 = (ic[3] == ii[i][r]) ? -3e38f : acc[i][3][r];
      s2[i][r] = fmaxf(fmaxf(t0, t1), fmaxf(t2, t3));
    }
#pragma unroll
  for (int m = 1; m < 16; m <<= 1)
#pragma unroll
    for (int i = 0; i < 4; ++i)
#pragma unroll
      for (int r = 0; r < 4; ++r)
        s2[i][r] = fmaxf(s2[i][r], __shfl_xor(s2[i][r], m));

  // owner-lane selection (compile-time indices only)
  const int c = l & 15, g16 = l >> 4;
  float fs1 = -3e38f, fs2 = -3e38f;
  unsigned fii = 0;
#pragma unroll
  for (int i = 0; i < 4; ++i) {
    if ((c >> 2) == i) {
      int rsel = c & 3;
      fs1 = (rsel == 0) ? mx[i][0] : (rsel == 1) ? mx[i][1] : (rsel == 2) ? mx[i][2] : mx[i][3];
      fii = (rsel == 0) ? ii[i][0] : (rsel == 1) ? ii[i][1] : (rsel == 2) ? ii[i][2] : ii[i][3];
      fs2 = (rsel == 0) ? s2[i][0] : (rsel == 1) ? s2[i][1] : (rsel == 2) ? s2[i][2] : s2[i][3];
    }
  }
  ull_t fp = ((ull_t)flipf(fs1) << 32) | fii;
  const int rib = wr * 64 + (c >> 2) * 16 + g16 * 4 + (c & 3);   // owned row in [0,128)

  // cross-wave (wc) merge via LDS (staging area dead after final __syncthreads)
  ull_t* lp = (ull_t*)lds;              // [2][128]
  float* ls2 = (float*)(lds + 2048);    // [2][128]
  lp[wc * 128 + rib] = fp; ls2[wc * 128 + rib] = fs2;
  __syncthreads();
  if (wc == 0) {
    ull_t op = lp[128 + rib];
    float os2 = ls2[128 + rib];
    ull_t lo = umin64(fp, op);
    fs2 = fmaxf(fmaxf(fs2, os2), unflipf((unsigned)(lo >> 32)));
    fp = umax64(fp, op);
    ppu[(size_t)(row0 + rib) * 64 + by] = fp;
    pps2[(size_t)(row0 + rib) * 64 + by] = fs2;
  }
}

// -------- combine: candidates = block top-1 cols within MARGIN; s2-hit blocks -> full scan --------
__global__ __launch_bounds__(256) void combine(const ull_t* __restrict__ ppu,
                                               const float* __restrict__ pps2,
                                               int* __restrict__ wl, int* __restrict__ wl2,
                                               int* __restrict__ counters) {
  int row = (blockIdx.x * 256 + threadIdx.x) >> 6;
  int l = threadIdx.x & 63;
  ull_t p = ppu[(size_t)row * 64 + l];
  float s2 = pps2[(size_t)row * 64 + l];
  ull_t gp = p;
#pragma unroll
  for (int m = 1; m < 64; m <<= 1) gp = umax64(gp, __shfl_xor(gp, m));
  float gs = unflipf((unsigned)(gp >> 32));
  float t = gs - MARGIN;
  float s1 = unflipf((unsigned)(p >> 32));
  bool cand = (s1 >= t);
  bool ovf = (s2 >= t);
  ull_t b1 = __ballot(cand);
  ull_t b2 = __ballot(ovf);
  int n1 = __popcll(b1), n2 = __popcll(b2);
  int base1 = 0, base2 = 0;
  if (l == 0) {
    base1 = atomicAdd(&counters[0], n1);
    if (n2) base2 = atomicAdd(&counters[1], n2);
  }
  base1 = __shfl(base1, 0); base2 = __shfl(base2, 0);
  ull_t below = (1ull << l) - 1ull;
  if (cand) {
    int col = (int)(0xFFFFFFFFu - (unsigned)(p & 0xFFFFFFFFu));
    wl[base1 + __popcll(b1 & below)] = (row << 13) | col;
  }
  if (ovf) wl2[base2 + __popcll(b2 & below)] = (row << 6) | l;
}

// -------- exact fp32 scoring of single candidate cols: one wave per entry --------
__global__ __launch_bounds__(256) void cand_exact(const float* __restrict__ x,
                                                  const float* __restrict__ embed,
                                                  const float* __restrict__ ehs,
                                                  const int* __restrict__ wl,
                                                  const int* __restrict__ counters,
                                                  ull_t* __restrict__ rowbest) {
  int wid = (blockIdx.x * 256 + threadIdx.x) >> 6;
  int l = threadIdx.x & 63;
  int count = counters[0];
  for (int eidx = wid; eidx < count; eidx += 16384) {
    int entry = wl[eidx];
    int row = entry >> 13, col = entry & 8191;
    float4 xa = *(const float4*)(x + (size_t)row * D_ + l * 8);
    float4 xc = *(const float4*)(x + (size_t)row * D_ + l * 8 + 4);
    float4 ea = *(const float4*)(embed + (size_t)col * D_ + l * 8);
    float4 ec = *(const float4*)(embed + (size_t)col * D_ + l * 8 + 4);
    float s = xa.x * ea.x + xa.y * ea.y + xa.z * ea.z + xa.w * ea.w
            + xc.x * ec.x + xc.y * ec.y + xc.z * ec.z + xc.w * ec.w;
#pragma unroll
    for (int m = 1; m < 64; m <<= 1) s += __shfl_xor(s, m);
    s -= ehs[col];
    if (l == 0) {
      ull_t packed = ((ull_t)flipf(s) << 32) | (0xFFFFFFFFu - (unsigned)col);
      atomicMax(&rowbest[row], packed);
    }
  }
}

// -------- full exact fp32 scan of s2-flagged (row, block): one wave per entry (rare) --------
__global__ __launch_bounds__(256) void fb_full(const float* __restrict__ x,
                                               const float* __restrict__ embed,
                                               const float* __restrict__ ehs,
                                               const int* __restrict__ wl2,
                                               const int* __restrict__ counters,
                                               ull_t* __restrict__ rowbest) {
  int wid = (blockIdx.x * 256 + threadIdx.x) >> 6;
  int l = threadIdx.x & 63;
  int count = counters[1];
  for (int eidx = wid; eidx < count; eidx += 16384) {
    int entry = wl2[eidx];
    int row = entry >> 6;
    int c0 = (entry & 63) * 128;
    const float* xr = x + (size_t)row * D_;
    const float* e0p = embed + (size_t)(c0 + l) * D_;
    const float* e1p = embed + (size_t)(c0 + 64 + l) * D_;
    float a0 = 0.f, a1 = 0.f;
    for (int d = 0; d < D_; d += 4) {
      float4 xv = *(const float4*)(xr + d);
      float4 v0 = *(const float4*)(e0p + d);
      float4 v1 = *(const float4*)(e1p + d);
      a0 = fmaf(v0.x, xv.x, fmaf(v0.y, xv.y, fmaf(v0.z, xv.z, fmaf(v0.w, xv.w, a0))));
      a1 = fmaf(v1.x, xv.x, fmaf(v1.y, xv.y, fmaf(v1.z, xv.z, fmaf(v1.w, xv.w, a1))));
    }
    float s0 = a0 - ehs[c0 + l];
    float s1 = a1 - ehs[c0 + 64 + l];
    ull_t p0 = ((ull_t)flipf(s0) << 32) | (0xFFFFFFFFu - (unsigned)(c0 + l));
    ull_t p1 = ((ull_t)flipf(s1) << 32) | (0xFFFFFFFFu - (unsigned)(c0 + 64 + l));
    ull_t packed = umax64(p0, p1);
#pragma unroll
    for (int m = 1; m < 64; m <<= 1) packed = umax64(packed, __shfl_xor(packed, m));
    if (l == 0) atomicMax(&rowbest[row], packed);
  }
}

// -------- write all outputs: gather embed[argmax] + index-as-float --------
__global__ __launch_bounds__(256) void gather(const float* __restrict__ embed,
                                              const ull_t* __restrict__ rowbest,
                                              float* __restrict__ out) {
  int row = (blockIdx.x * 256 + threadIdx.x) >> 6;
  int l = threadIdx.x & 63;
  ull_t p = rowbest[row];
  int idx = (int)(0xFFFFFFFFu - (unsigned)(p & 0xFFFFFFFFu));
  const float4* src = (const float4*)(embed + (size_t)idx * D_);
  float4* dst = (float4*)(out + (size_t)row * D_);
  dst[l] = src[l];
  dst[l + 64] = src[l + 64];
  if (l == 0) out[(size_t)N_ * D_ + row] = (float)idx;
}

extern "C" void kernel_launch(void* const* d_in, const int* in_sizes, int n_in,
                              void* d_out, int out_size, void* d_ws, size_t ws_size,
                              hipStream_t stream) {
  const float* x = (const float*)d_in[0];     // [16384, 512]
  const float* e = (const float*)d_in[1];     // [8192, 512]
  float* out = (float*)d_out;

  char* ws = (char*)d_ws;
  // region A (0..16MB): xbt during conv/dist; worklists alias it afterwards
  char* xbt = ws;                                       // 16 MB
  int* wl = (int*)ws;                                   // 4 MB (candidate entries)
  int* wl2 = (int*)(ws + 4194304);                      // 4 MB (overflow entries)
  int* counters = (int*)(ws + 8388608);                 // 8 B
  ull_t* rowbest = (ull_t*)(ws + 8388672);              // 128 KB
  char* ebt = ws + 16777216;                            // 8 MB
  float* ehs = (float*)(ws + 25165824);                 // 32 KB
  ull_t* ppu = (ull_t*)(ws + 25198592);                 // 8 MB (N_*64 ull)
  float* pps2 = (float*)(ws + 33587200);                // 4 MB (N_*64 float)

  conv_x<<<1024, 256, 0, stream>>>(x, xbt);
  conv_e<<<512, 256, 0, stream>>>(e, ebt, ehs);
  dist_mfma<<<dim3(128, 64), 256, 0, stream>>>(xbt, ebt, ehs, ppu, pps2);
  init_ws<<<64, 256, 0, stream>>>(counters, rowbest);   // after dist_mfma: aliases xbt
  combine<<<4096, 256, 0, stream>>>(ppu, pps2, wl, wl2, counters);
  cand_exact<<<4096, 256, 0, stream>>>(x, e, ehs, wl, counters, rowbest);
  fb_full<<<4096, 256, 0, stream>>>(x, e, ehs, wl2, counters, rowbest);
  gather<<<4096, 256, 0, stream>>>(e, rowbest, out);
}

// Round 12
// 251.309 us; speedup vs baseline: 1.8978x; 1.8816x over previous
//
#include <hip/hip_runtime.h>
#include <cstddef>
#include <cstdint>

typedef unsigned short ushort_t;
typedef unsigned long long ull_t;
typedef __attribute__((ext_vector_type(8))) short short8;
typedef __attribute__((ext_vector_type(4))) float f32x4;

constexpr int D_ = 512, K_ = 8192, N_ = 16384;
constexpr float MARGIN = 0.75f;   // >= 2*eps of bf16-MFMA score error (max-tail ~0.45)

// RNE float->bf16 (data has no NaN)
__device__ __forceinline__ ushort_t f2bf(float f) {
  unsigned u = __float_as_uint(f);
  return (ushort_t)((u + 0x7FFFu + ((u >> 16) & 1u)) >> 16);
}
// order-preserving float->uint flip (max-compatible)
__device__ __forceinline__ unsigned flipf(float s) {
  unsigned u = __float_as_uint(s);
  return (u & 0x80000000u) ? ~u : (u | 0x80000000u);
}
__device__ __forceinline__ float unflipf(unsigned m) {
  unsigned u = (m & 0x80000000u) ? (m ^ 0x80000000u) : ~m;
  return __uint_as_float(u);
}
__device__ __forceinline__ ull_t umax64(ull_t a, ull_t b) { return a > b ? a : b; }
__device__ __forceinline__ ull_t umin64(ull_t a, ull_t b) { return a < b ? a : b; }

__device__ __forceinline__ void gld16(void* l, const void* g) {
  __builtin_amdgcn_global_load_lds((const __attribute__((address_space(1))) void*)g,
                                   (__attribute__((address_space(3))) void*)l, 16, 0, 0);
}

// -------- fused convert: x and e -> bf16 permuted layout (+ehs), coalesced reads --------
// dst layout: [tile][g(16)][kq(4)][r(128)] 16B chunks.
// blocks 0..1023: x (128 tiles x 8 rowgroups); blocks 1024..1535: e (64 tiles x 8 rowgroups)
__global__ __launch_bounds__(256) void conv_all(const float* __restrict__ x,
                                                const float* __restrict__ e,
                                                char* __restrict__ xbt, char* __restrict__ ebt,
                                                float* __restrict__ ehs) {
  const int g = threadIdx.x & 15, rr = threadIdx.x >> 4;
  if ((int)blockIdx.x < 1024) {
    const int tile = blockIdx.x >> 3, rg = blockIdx.x & 7;
    const int r = rg * 16 + rr;
    const float4* src = (const float4*)(x + ((size_t)(tile * 128 + r)) * D_ + g * 32);
    float4 f[8];
#pragma unroll
    for (int q = 0; q < 8; ++q) f[q] = src[q];
    char* dbase = xbt + (size_t)tile * 131072 + g * 8192 + r * 16;
#pragma unroll
    for (int kq = 0; kq < 4; ++kq) {
      float4 a = f[kq * 2], b = f[kq * 2 + 1];
      short8 v;
      v[0] = (short)f2bf(a.x); v[1] = (short)f2bf(a.y); v[2] = (short)f2bf(a.z); v[3] = (short)f2bf(a.w);
      v[4] = (short)f2bf(b.x); v[5] = (short)f2bf(b.y); v[6] = (short)f2bf(b.z); v[7] = (short)f2bf(b.w);
      *(short8*)(dbase + kq * 2048) = v;
    }
  } else {
    const int bid = blockIdx.x - 1024;
    const int tile = bid >> 3, rg = bid & 7;
    const int r = rg * 16 + rr;
    const int col = tile * 128 + r;
    const float4* src = (const float4*)(e + (size_t)col * D_ + g * 32);
    float4 f[8];
    float ss = 0.f;
#pragma unroll
    for (int q = 0; q < 8; ++q) {
      f[q] = src[q];
      ss += f[q].x * f[q].x + f[q].y * f[q].y + f[q].z * f[q].z + f[q].w * f[q].w;
    }
    char* dbase = ebt + (size_t)tile * 131072 + g * 8192 + r * 16;
#pragma unroll
    for (int kq = 0; kq < 4; ++kq) {
      float4 a = f[kq * 2], b = f[kq * 2 + 1];
      short8 v;
      v[0] = (short)f2bf(a.x); v[1] = (short)f2bf(a.y); v[2] = (short)f2bf(a.z); v[3] = (short)f2bf(a.w);
      v[4] = (short)f2bf(b.x); v[5] = (short)f2bf(b.y); v[6] = (short)f2bf(b.z); v[7] = (short)f2bf(b.w);
      *(short8*)(dbase + kq * 2048) = v;
    }
#pragma unroll
    for (int m = 1; m < 16; m <<= 1) ss += __shfl_xor(ss, m);
    if (g == 0) ehs[col] = 0.5f * ss;
  }
}

// -------- MFMA scoring: per (row, 128-col block) packed top-1 (score|invcol) + s2 --------
// grid (128,64); XCD-swizzled; BK=32; double-buffered LDS with __syncthreads per K-step
// (R9's proven-race-free structure: the prefetch DMA flies during ds_read+MFMA, and the
// barrier's vmcnt(0) drain lands it; counted-vmcnt variants raced — reverted, m152 lesson).
__global__ __launch_bounds__(256, 3) void dist_mfma(const char* __restrict__ xbt,
                                                    const char* __restrict__ ebt,
                                                    const float* __restrict__ ehs,
                                                    ull_t* __restrict__ ppu,
                                                    float* __restrict__ pps2) {
  __shared__ alignas(16) char lds[32768];   // [buf(2)][A(8K)|B(8K)]
  const int tid = threadIdx.x, w = tid >> 6, l = tid & 63;
  // XCD-aware bijective remap: XCD k owns col-tiles [8k,8k+8), sweeps them innermost
  const int fid = blockIdx.x + blockIdx.y * 128;
  const int k8 = fid & 7, j = fid >> 3;
  const int by = k8 * 8 + (j & 7), bx = j >> 3;
  const int row0 = bx * 128, col0 = by * 128;
  const int wr = w >> 1, wc = w & 1;
  const char* xsrc = xbt + (size_t)bx * 131072;
  const char* esrc = ebt + (size_t)by * 131072;

  // prologue: stage slab 0 into buf0 (4 loads/wave)
#pragma unroll
  for (int i = 0; i < 2; ++i) {
    gld16(lds + w * 2048 + i * 1024, xsrc + w * 2048 + i * 1024 + l * 16);
    gld16(lds + 8192 + w * 2048 + i * 1024, esrc + w * 2048 + i * 1024 + l * 16);
  }
  __syncthreads();

  f32x4 acc[4][4] = {};
  for (int g = 0; g < 16; ++g) {
    char* cbase = lds + (g & 1) * 16384;
    // prefetch next slab into the other buffer (flies during ds_read+MFMA below)
    if (g < 15) {
      char* nbase = lds + ((g + 1) & 1) * 16384;
#pragma unroll
      for (int i = 0; i < 2; ++i) {
        gld16(nbase + w * 2048 + i * 1024, xsrc + (g + 1) * 8192 + w * 2048 + i * 1024 + l * 16);
        gld16(nbase + 8192 + w * 2048 + i * 1024, esrc + (g + 1) * 8192 + w * 2048 + i * 1024 + l * 16);
      }
    }
    short8 a[4], b[4];
#pragma unroll
    for (int i = 0; i < 4; ++i)
      a[i] = *(const short8*)(cbase + (l >> 4) * 2048 + (wr * 64 + i * 16 + (l & 15)) * 16);
#pragma unroll
    for (int jj = 0; jj < 4; ++jj)
      b[jj] = *(const short8*)(cbase + 8192 + (l >> 4) * 2048 + (wc * 64 + jj * 16 + (l & 15)) * 16);
#pragma unroll
    for (int i = 0; i < 4; ++i)
#pragma unroll
      for (int jj = 0; jj < 4; ++jj)
        acc[i][jj] = __builtin_amdgcn_mfma_f32_16x16x32_bf16(a[i], b[jj], acc[i][jj], 0, 0, 0);
    __syncthreads();   // drains vm+lgkm: next buffer ready, current buffer free to overwrite
  }

  // ---- epilogue (f32/u32 three-phase; no u64 until the final pack) ----
  float eh[4];
  unsigned ic[4];
#pragma unroll
  for (int jj = 0; jj < 4; ++jj) {
    int col = col0 + wc * 64 + jj * 16 + (l & 15);
    eh[jj] = ehs[col];
    ic[jj] = 0xFFFFFFFFu - (unsigned)col;   // larger == smaller col on score tie; never 0
  }
#pragma unroll
  for (int i = 0; i < 4; ++i)
#pragma unroll
    for (int jj = 0; jj < 4; ++jj)
#pragma unroll
      for (int r = 0; r < 4; ++r)
        acc[i][jj][r] -= eh[jj];

  // Phase A: row max (all-reduce over the 16 col-lanes)
  float mx[4][4];
#pragma unroll
  for (int i = 0; i < 4; ++i)
#pragma unroll
    for (int r = 0; r < 4; ++r)
      mx[i][r] = fmaxf(fmaxf(acc[i][0][r], acc[i][1][r]), fmaxf(acc[i][2][r], acc[i][3][r]));
#pragma unroll
  for (int m = 1; m < 16; m <<= 1)
#pragma unroll
    for (int i = 0; i < 4; ++i)
#pragma unroll
      for (int r = 0; r < 4; ++r)
        mx[i][r] = fmaxf(mx[i][r], __shfl_xor(mx[i][r], m));

  // Phase B: index (max inverted-col among elements equal to max)
  unsigned ii[4][4];
#pragma unroll
  for (int i = 0; i < 4; ++i)
#pragma unroll
    for (int r = 0; r < 4; ++r) {
      unsigned t0 = (acc[i][0][r] == mx[i][r]) ? ic[0] : 0u;
      unsigned t1 = (acc[i][1][r] == mx[i][r]) ? ic[1] : 0u;
      unsigned t2 = (acc[i][2][r] == mx[i][r]) ? ic[2] : 0u;
      unsigned t3 = (acc[i][3][r] == mx[i][r]) ? ic[3] : 0u;
      unsigned u01 = t0 > t1 ? t0 : t1, u23 = t2 > t3 ? t2 : t3;
      ii[i][r] = u01 > u23 ? u01 : u23;
    }
#pragma unroll
  for (int m = 1; m < 16; m <<= 1)
#pragma unroll
    for (int i = 0; i < 4; ++i)
#pragma unroll
      for (int r = 0; r < 4; ++r) {
        unsigned o = __shfl_xor(ii[i][r], m);
        ii[i][r] = ii[i][r] > o ? ii[i][r] : o;
      }

  // Phase C: s2 = max excluding exactly the chosen instance (ties -> s2 == max -> overflow)
  float s2[4][4];
#pragma unroll
  for (int i = 0; i < 4; ++i)
#pragma unroll
    for (int r = 0; r < 4; ++r) {
      float t0 = (ic[0] == ii[i][r]) ? -3e38f : acc[i][0][r];
      float t1 = (ic[1] == ii[i][r]) ? -3e38f : acc[i][1][r];
      float t2 = (ic[2] == ii[i][r]) ? -3e38f : acc[i][2][r];
      float t3 = (ic[3] == ii[i][r]) ? -3e38f : acc[i][3][r];
      s2[i][r] = fmaxf(fmaxf(t0, t1), fmaxf(t2, t3));
    }
#pragma unroll
  for (int m = 1; m < 16; m <<= 1)
#pragma unroll
    for (int i = 0; i < 4; ++i)
#pragma unroll
      for (int r = 0; r < 4; ++r)
        s2[i][r] = fmaxf(s2[i][r], __shfl_xor(s2[i][r], m));

  // owner-lane selection (compile-time indices only)
  const int c = l & 15, g16 = l >> 4;
  float fs1 = -3e38f, fs2 = -3e38f;
  unsigned fii = 0;
#pragma unroll
  for (int i = 0; i < 4; ++i) {
    if ((c >> 2) == i) {
      int rsel = c & 3;
      fs1 = (rsel == 0) ? mx[i][0] : (rsel == 1) ? mx[i][1] : (rsel == 2) ? mx[i][2] : mx[i][3];
      fii = (rsel == 0) ? ii[i][0] : (rsel == 1) ? ii[i][1] : (rsel == 2) ? ii[i][2] : ii[i][3];
      fs2 = (rsel == 0) ? s2[i][0] : (rsel == 1) ? s2[i][1] : (rsel == 2) ? s2[i][2] : s2[i][3];
    }
  }
  ull_t fp = ((ull_t)flipf(fs1) << 32) | fii;
  const int rib = wr * 64 + (c >> 2) * 16 + g16 * 4 + (c & 3);   // owned row in [0,128)

  // cross-wave (wc) merge via LDS (staging area dead after final __syncthreads)
  ull_t* lp = (ull_t*)lds;              // [2][128]
  float* ls2 = (float*)(lds + 2048);    // [2][128]
  lp[wc * 128 + rib] = fp; ls2[wc * 128 + rib] = fs2;
  __syncthreads();
  if (wc == 0) {
    ull_t op = lp[128 + rib];
    float os2 = ls2[128 + rib];
    ull_t lo = umin64(fp, op);
    fs2 = fmaxf(fmaxf(fs2, os2), unflipf((unsigned)(lo >> 32)));
    fp = umax64(fp, op);
    ppu[(size_t)(row0 + rib) * 64 + by] = fp;
    pps2[(size_t)(row0 + rib) * 64 + by] = fs2;
  }
}

// -------- finalize: combine + in-wave exact rescore + gather, one wave per row --------
__global__ __launch_bounds__(256) void finalize(const float* __restrict__ x,
                                                const float* __restrict__ embed,
                                                const float* __restrict__ ehs,
                                                const ull_t* __restrict__ ppu,
                                                const float* __restrict__ pps2,
                                                float* __restrict__ out) {
  const int row = (blockIdx.x * 256 + threadIdx.x) >> 6;
  const int l = threadIdx.x & 63;
  ull_t p = ppu[(size_t)row * 64 + l];
  float s2 = pps2[(size_t)row * 64 + l];
  ull_t gp = p;
#pragma unroll
  for (int m = 1; m < 64; m <<= 1) gp = umax64(gp, __shfl_xor(gp, m));
  float gs = unflipf((unsigned)(gp >> 32));
  float t = gs - MARGIN;
  bool cand = (unflipf((unsigned)(p >> 32)) >= t);
  bool ovf = (s2 >= t);
  ull_t b1 = __ballot(cand);
  ull_t b2 = __ballot(ovf);
  int idx;
  if (__popcll(b1) == 1 && b2 == 0ull) {
    // provably exact: every other col's fp32 score < gs - MARGIN + eps <= winner's fp32 score
    idx = (int)(0xFFFFFFFFu - (unsigned)(gp & 0xFFFFFFFFu));
  } else {
    const float4* xr4 = (const float4*)(x + (size_t)row * D_ + l * 8);
    float4 xa = xr4[0], xc = xr4[1];
    ull_t best = 0ull;
    ull_t bb = b1;
    while (bb) {                       // exact-score each candidate block-top-1 col
      int b = (int)__builtin_ctzll(bb);
      bb &= bb - 1;
      ull_t pb = __shfl(p, b);
      int col = (int)(0xFFFFFFFFu - (unsigned)(pb & 0xFFFFFFFFu));
      const float4* er4 = (const float4*)(embed + (size_t)col * D_ + l * 8);
      float4 ea = er4[0], ec = er4[1];
      float s = xa.x * ea.x + xa.y * ea.y + xa.z * ea.z + xa.w * ea.w
              + xc.x * ec.x + xc.y * ec.y + xc.z * ec.z + xc.w * ec.w;
#pragma unroll
      for (int m = 1; m < 64; m <<= 1) s += __shfl_xor(s, m);
      s -= ehs[col];
      best = umax64(best, ((ull_t)flipf(s) << 32) | (0xFFFFFFFFu - (unsigned)col));
    }
    while (b2) {                       // full exact scan of s2-overflow blocks (rare)
      int b = (int)__builtin_ctzll(b2);
      b2 &= b2 - 1;
      int c0 = b * 128;
      const float* xr = x + (size_t)row * D_;
      const float* e0p = embed + (size_t)(c0 + l) * D_;
      const float* e1p = embed + (size_t)(c0 + 64 + l) * D_;
      float a0 = 0.f, a1 = 0.f;
      for (int d = 0; d < D_; d += 4) {
        float4 xv = *(const float4*)(xr + d);
        float4 v0 = *(const float4*)(e0p + d);
        float4 v1 = *(const float4*)(e1p + d);
        a0 = fmaf(v0.x, xv.x, fmaf(v0.y, xv.y, fmaf(v0.z, xv.z, fmaf(v0.w, xv.w, a0))));
        a1 = fmaf(v1.x, xv.x, fmaf(v1.y, xv.y, fmaf(v1.z, xv.z, fmaf(v1.w, xv.w, a1))));
      }
      float s0 = a0 - ehs[c0 + l];
      float s1 = a1 - ehs[c0 + 64 + l];
      ull_t p0 = ((ull_t)flipf(s0) << 32) | (0xFFFFFFFFu - (unsigned)(c0 + l));
      ull_t p1 = ((ull_t)flipf(s1) << 32) | (0xFFFFFFFFu - (unsigned)(c0 + 64 + l));
      ull_t pk = umax64(p0, p1);
#pragma unroll
      for (int m = 1; m < 64; m <<= 1) pk = umax64(pk, __shfl_xor(pk, m));
      best = umax64(best, pk);
    }
    idx = (int)(0xFFFFFFFFu - (unsigned)(best & 0xFFFFFFFFu));
  }
  const float4* src = (const float4*)(embed + (size_t)idx * D_);
  float4* dst = (float4*)(out + (size_t)row * D_);
  dst[l] = src[l];
  dst[l + 64] = src[l + 64];
  if (l == 0) out[(size_t)N_ * D_ + row] = (float)idx;
}

extern "C" void kernel_launch(void* const* d_in, const int* in_sizes, int n_in,
                              void* d_out, int out_size, void* d_ws, size_t ws_size,
                              hipStream_t stream) {
  const float* x = (const float*)d_in[0];     // [16384, 512]
  const float* e = (const float*)d_in[1];     // [8192, 512]
  float* out = (float*)d_out;

  char* ws = (char*)d_ws;
  char* xbt = ws;                                       // 16 MB
  char* ebt = ws + 16777216;                            // 8 MB
  float* ehs = (float*)(ws + 25165824);                 // 32 KB
  ull_t* ppu = (ull_t*)(ws + 25198592);                 // 8 MB (N_*64 ull)
  float* pps2 = (float*)(ws + 33587200);                // 4 MB (N_*64 float)

  conv_all<<<1536, 256, 0, stream>>>(x, e, xbt, ebt, ehs);
  dist_mfma<<<dim3(128, 64), 256, 0, stream>>>(xbt, ebt, ehs, ppu, pps2);
  finalize<<<4096, 256, 0, stream>>>(x, e, ehs, ppu, pps2, out);
}